// Round 1
// baseline (668.084 us; speedup 1.0000x reference)
//
#include <hip/hip_runtime.h>
#include <math.h>

#define NLAT 361
#define NLON 720
#define EPSF 1e-7f
#define TWOPI_N 6.283185307179586e+0  // 2*pi; step = TWOPI_N/720

// ---------------------------------------------------------------------------
// Kernel 1: real DFT over longitude, two latitude rows per block (shared
// rotators), fused quadrature weight, output in leg-friendly layout:
//   GG[m][j][bc] = float4( Fp.re, Fp.im, Ft.re, Ft.im ) * (2pi/720) * w[j]
// m = 0..359 (Nyquist bin 360 is dead under the triangular mask).
// Thread m (0..180) produces bins m and 360-m via n-parity routing; per-lane
// incremental complex rotators replace the LDS twiddle table (no bank
// conflicts, no index ALU).
// ---------------------------------------------------------------------------
__global__ void dft_kernel(const float* __restrict__ pred,
                           const float* __restrict__ targ,
                           const float* __restrict__ wq,
                           float4* __restrict__ GG) {
  const int blk = blockIdx.x;          // 16 * 181 blocks
  const int bc  = blk / 181;
  const int p   = blk - bc * 181;
  const int j0  = 2 * p;
  const int j1  = (j0 + 1 <= 360) ? j0 + 1 : j0;   // row 360 pairs with itself

  const float* fp0 = pred + ((size_t)bc * NLAT + j0) * NLON;
  const float* ft0 = targ + ((size_t)bc * NLAT + j0) * NLON;
  const float* fp1 = pred + ((size_t)bc * NLAT + j1) * NLON;
  const float* ft1 = targ + ((size_t)bc * NLAT + j1) * NLON;

  __shared__ float4 eo[2][360];        // (e_p, o_p, e_t, o_t), n=1..359
  const int tid = threadIdx.x;
  for (int idx = tid; idx < 720; idx += 192) {
    int r = idx / 360, n = idx - 360 * r;
    if (n >= 1) {
      const float* a = r ? fp1 : fp0;
      const float* b = r ? ft1 : ft0;
      float a1 = a[n], a2 = a[NLON - n], b1 = b[n], b2 = b[NLON - n];
      eo[r][n] = make_float4(a1 + a2, a1 - a2, b1 + b2, b1 - b2);
    }
  }
  __syncthreads();

  const int m = tid;
  if (m > 180) return;

  // rotators: chain1 at angle (2k-1)*m*t0, chain2 at (2k)*m*t0; step 2m*t0
  float c1, s1, c2, s2, cs, ss;
  {
    float a1 = (float)(TWOPI_N / 720.0 * (double)m);
    float a2 = (float)(TWOPI_N / 720.0 * (double)(2 * m));
    sincosf(a1, &s1, &c1);
    sincosf(a2, &ss, &cs);
    c2 = cs; s2 = ss;
  }

  float CeP0 = 0.f, CoP0 = 0.f, SeP0 = 0.f, SoP0 = 0.f;
  float CeT0 = 0.f, CoT0 = 0.f, SeT0 = 0.f, SoT0 = 0.f;
  float CeP1 = 0.f, CoP1 = 0.f, SeP1 = 0.f, SoP1 = 0.f;
  float CeT1 = 0.f, CoT1 = 0.f, SeT1 = 0.f, SoT1 = 0.f;

#pragma unroll 2
  for (int k = 1; k <= 179; ++k) {
    float4 u0 = eo[0][2 * k - 1], v0 = eo[0][2 * k];
    float4 u1 = eo[1][2 * k - 1], v1 = eo[1][2 * k];
    CoP0 += u0.x * c1; SoP0 += u0.y * s1; CoT0 += u0.z * c1; SoT0 += u0.w * s1;
    CeP0 += v0.x * c2; SeP0 += v0.y * s2; CeT0 += v0.z * c2; SeT0 += v0.w * s2;
    CoP1 += u1.x * c1; SoP1 += u1.y * s1; CoT1 += u1.z * c1; SoT1 += u1.w * s1;
    CeP1 += v1.x * c2; SeP1 += v1.y * s2; CeT1 += v1.z * c2; SeT1 += v1.w * s2;
    float nc1 = c1 * cs - s1 * ss, ns1 = s1 * cs + c1 * ss;
    c1 = nc1; s1 = ns1;
    float nc2 = c2 * cs - s2 * ss, ns2 = s2 * cs + c2 * ss;
    c2 = nc2; s2 = ns2;
  }
  { // tail n = 359 (odd); c1,s1 now at angle 359*m*t0
    float4 u0 = eo[0][359], u1 = eo[1][359];
    CoP0 += u0.x * c1; SoP0 += u0.y * s1; CoT0 += u0.z * c1; SoT0 += u0.w * s1;
    CoP1 += u1.x * c1; SoP1 += u1.y * s1; CoT1 += u1.z * c1; SoT1 += u1.w * s1;
  }

  const float sgn = (m & 1) ? -1.f : 1.f;
  const float t0w = (float)(TWOPI_N / 720.0);
  // row 0
  {
    float baseP = fp0[0] + sgn * fp0[360];
    float baseT = ft0[0] + sgn * ft0[360];
    float sc = t0w * wq[j0];
    float reP = baseP + CeP0 + CoP0, imP = -(SeP0 + SoP0);
    float reT = baseT + CeT0 + CoT0, imT = -(SeT0 + SoT0);
    GG[((size_t)m * NLAT + j0) * 16 + bc] =
        make_float4(reP * sc, imP * sc, reT * sc, imT * sc);
    if (m >= 1 && m <= 179) {
      int m2 = 360 - m;
      float reP2 = baseP + CeP0 - CoP0, imP2 = SeP0 - SoP0;
      float reT2 = baseT + CeT0 - CoT0, imT2 = SeT0 - SoT0;
      GG[((size_t)m2 * NLAT + j0) * 16 + bc] =
          make_float4(reP2 * sc, imP2 * sc, reT2 * sc, imT2 * sc);
    }
  }
  // row 1 (duplicate write when j1==j0 is benign: same thread, same value)
  {
    float baseP = fp1[0] + sgn * fp1[360];
    float baseT = ft1[0] + sgn * ft1[360];
    float sc = t0w * wq[j1];
    float reP = baseP + CeP1 + CoP1, imP = -(SeP1 + SoP1);
    float reT = baseT + CeT1 + CoT1, imT = -(SeT1 + SoT1);
    GG[((size_t)m * NLAT + j1) * 16 + bc] =
        make_float4(reP * sc, imP * sc, reT * sc, imT * sc);
    if (m >= 1 && m <= 179) {
      int m2 = 360 - m;
      float reP2 = baseP + CeP1 - CoP1, imP2 = SeP1 - SoP1;
      float reT2 = baseT + CeT1 - CoT1, imT2 = SeT1 - SoT1;
      GG[((size_t)m2 * NLAT + j1) * 16 + bc] =
          make_float4(reP2 * sc, imP2 * sc, reT2 * sc, imT2 * sc);
    }
  }
}

// ---------------------------------------------------------------------------
// Kernel 2 (rewritten): Legendre contraction + triangular PSD/cross-spectrum.
// Parity trick unchanged (only j=0..180 of leg is read).
// New decomposition for latency hiding & load reuse:
//   block = 128 thr = 16 bc x 4 j-lanes x 2 l-groups; 16 l-rows x 2 m per
//   block; each THREAD owns 8 l-rows -> 32 acc-FMAs per pair of GG loads
//   (was 16 FMAs with 4x redundant loads). Explicit A/B prefetch keeps two
//   global loads in flight per wave. Grid = 2208 blocks (8.6/CU) with
//   __launch_bounds__(128,4) -> ~16 waves/CU resident.
// Reduction over the 4 j-lanes = shfl_xor(16/32); l-groups are whole waves
// so no cross-wave reduction is needed.
// ---------------------------------------------------------------------------
#define ACC8()                                                       \
  do {                                                               \
    ca[0][0] += g0.x * u0x; ca[0][1] += g0.x * u0y;                  \
    ca[0][2] += g0.x * u0z; ca[0][3] += g0.x * u0w;                  \
    ca[1][0] += g0.y * u1x; ca[1][1] += g0.y * u1y;                  \
    ca[1][2] += g0.y * u1z; ca[1][3] += g0.y * u1w;                  \
    ca[2][0] += g0.z * u0x; ca[2][1] += g0.z * u0y;                  \
    ca[2][2] += g0.z * u0z; ca[2][3] += g0.z * u0w;                  \
    ca[3][0] += g0.w * u1x; ca[3][1] += g0.w * u1y;                  \
    ca[3][2] += g0.w * u1z; ca[3][3] += g0.w * u1w;                  \
    ca[4][0] += g1.x * u0x; ca[4][1] += g1.x * u0y;                  \
    ca[4][2] += g1.x * u0z; ca[4][3] += g1.x * u0w;                  \
    ca[5][0] += g1.y * u1x; ca[5][1] += g1.y * u1y;                  \
    ca[5][2] += g1.y * u1z; ca[5][3] += g1.y * u1w;                  \
    ca[6][0] += g1.z * u0x; ca[6][1] += g1.z * u0y;                  \
    ca[6][2] += g1.z * u0z; ca[6][3] += g1.z * u0w;                  \
    ca[7][0] += g1.w * u1x; ca[7][1] += g1.w * u1y;                  \
    ca[7][2] += g1.w * u1z; ca[7][3] += g1.w * u1w;                  \
  } while (0)

__global__ __launch_bounds__(128, 4)
void leg_kernel(const float* __restrict__ leg,
                const float4* __restrict__ GG,
                float* __restrict__ S) {
  int bid = blockIdx.x;
  int lt = 0, accb = 0;
  while (bid >= accb + 8 * (lt + 1)) { accb += 8 * (lt + 1); ++lt; }
  const int l0 = lt * 16;
  const int m0 = (bid - accb) * 2;

  __shared__ float sLg[181][20];   // transposed tile, stride 20 (16B-aligned,
                                   // conflict-free b128 reads)
  const int tid = threadIdx.x;
  const int bc = tid & 15;         // 0..15 (consecutive bc -> coalesced GG)
  const int jg = (tid >> 4) & 3;   // 0..3  (j-lanes: lane bits 4..5)
  const int lg = tid >> 6;         // 0..1  (l-group = wave id; rows lg*8..+7)

  float racc[8][4];
#pragma unroll
  for (int r = 0; r < 8; ++r)
#pragma unroll
    for (int c = 0; c < 4; ++c) racc[r][c] = 0.f;

  for (int mi = 0; mi < 2; ++mi) {
    const int m = m0 + mi;
    if (m > 359) break;            // uniform across block
    if (mi) __syncthreads();
    // stage leg[l0..l0+15][m][0..180] transposed (coalesced global read)
    for (int idx = tid; idx < 16 * 181; idx += 128) {
      int lp = idx / 181, j = idx - lp * 181;
      int l = l0 + lp;
      sLg[j][lp] = (l <= 360) ? leg[((size_t)l * NLAT + m) * NLAT + j] : 0.f;
    }
    __syncthreads();

    // parity of row r=0 of each l-group is (l0+m)&1 (lg*8 is even).
    // u0 = A + sgn*B serves even r, u1 = A - sgn*B serves odd r.
    const float sgn  = ((l0 + m) & 1) ? -1.f : 1.f;
    const float msgn = -sgn;
    const float4* gm = GG + (size_t)m * (NLAT * 16);

    float ca[8][4];
#pragma unroll
    for (int r = 0; r < 8; ++r)
#pragma unroll
      for (int c = 0; c < 4; ++c) ca[r][c] = 0.f;

    // main loop over j = jg, jg+4, ..., < 180, with A/B prefetch
    float4 A = gm[jg * 16 + bc];
    float4 B = gm[(360 - jg) * 16 + bc];
    int j = jg;
    while (true) {
      const int jn = j + 4;
      const bool more = (jn < 180);
      float4 An, Bn;
      if (more) {
        An = gm[jn * 16 + bc];
        Bn = gm[(360 - jn) * 16 + bc];
      }
      float u0x = fmaf(sgn,  B.x, A.x), u0y = fmaf(sgn,  B.y, A.y);
      float u0z = fmaf(sgn,  B.z, A.z), u0w = fmaf(sgn,  B.w, A.w);
      float u1x = fmaf(msgn, B.x, A.x), u1y = fmaf(msgn, B.y, A.y);
      float u1z = fmaf(msgn, B.z, A.z), u1w = fmaf(msgn, B.w, A.w);
      const float* lrow = &sLg[j][lg * 8];
      float4 g0 = *(const float4*)lrow;
      float4 g1 = *(const float4*)(lrow + 4);
      ACC8();
      if (!more) break;
      j = jn; A = An; B = Bn;
    }
    // center j = 180 (self-paired, half weight) handled by jg==0 lanes
    if (jg == 0) {
      float4 Ac = gm[180 * 16 + bc];
      const float h0 = 0.5f + 0.5f * sgn;   // 1 if even parity else 0
      const float h1 = 0.5f - 0.5f * sgn;
      float u0x = h0 * Ac.x, u0y = h0 * Ac.y, u0z = h0 * Ac.z, u0w = h0 * Ac.w;
      float u1x = h1 * Ac.x, u1y = h1 * Ac.y, u1z = h1 * Ac.z, u1w = h1 * Ac.w;
      const float* lrow = &sLg[180][lg * 8];
      float4 g0 = *(const float4*)lrow;
      float4 g1 = *(const float4*)(lrow + 4);
      ACC8();
    }

    // reduce across the 4 j-lanes (lane bits 4..5)
#pragma unroll
    for (int r = 0; r < 8; ++r)
#pragma unroll
      for (int c = 0; c < 4; ++c) {
        ca[r][c] += __shfl_xor(ca[r][c], 16);
        ca[r][c] += __shfl_xor(ca[r][c], 32);
      }
    const float ef = (m == 0) ? 1.f : 2.f;
#pragma unroll
    for (int r = 0; r < 8; ++r) {
      float pr = ca[r][0], pi = ca[r][1], tr = ca[r][2], ti = ca[r][3];
      racc[r][0] += ef * (pr * pr + pi * pi);
      racc[r][1] += ef * (tr * tr + ti * ti);
      racc[r][2] += ef * (pr * tr + pi * ti);
      racc[r][3] += ef * (pr * ti - pi * tr);
    }
  }

  if ((tid & 0x30) == 0) {   // jg == 0 lanes: 16 bc x 2 waves
#pragma unroll
    for (int r = 0; r < 8; ++r) {
      int l = l0 + lg * 8 + r;
      if (l < 360) {
        float* sp = S + ((size_t)bc * 360 + l) * 4;
        atomicAdd(sp + 0, racc[r][0]);
        atomicAdd(sp + 1, racc[r][1]);
        atomicAdd(sp + 2, racc[r][2]);
        atomicAdd(sp + 3, racc[r][3]);
      }
    }
  }
}

// ---------------------------------------------------------------------------
// Kernel 3: final loss epilogue + reduction. One block.
// ---------------------------------------------------------------------------
__global__ void loss_kernel(const float* __restrict__ S,
                            const float* __restrict__ wts,
                            float* __restrict__ out) {
  const int tid = threadIdx.x;
  float acc = 0.f;
  for (int i = tid; i < 16 * 360; i += 256) {
    int bc = i / 360;
    const float* sp = S + (size_t)i * 4;
    float pp = sp[0] + EPSF;
    float tp = sp[1] + EPSF;
    float sr = sp[2], si = sp[3];
    float mag   = sqrtf(sr * sr + si * si);
    float denom = sqrtf(pp * tp + EPSF);
    float coh   = mag / (denom + EPSF);
    coh = fminf(fmaxf(coh, 0.f), 1.f);
    float sqp = sqrtf(pp), sqt = sqrtf(tp);
    float amp = (sqp - sqt) * (sqp - sqt);
    float dec = 2.f * fmaxf(pp, tp) * (1.f - coh);
    acc += (amp + dec) * wts[bc & 7];
  }
  __shared__ float red[4];
#pragma unroll
  for (int off = 32; off > 0; off >>= 1) acc += __shfl_xor(acc, off, 64);
  if ((tid & 63) == 0) red[tid >> 6] = acc;
  __syncthreads();
  if (tid == 0) {
    float loss = (red[0] + red[1] + red[2] + red[3]) / (360.f * 16.f);
    out[0] = isnan(loss) ? 1e6f : loss;
  }
}

// ---------------------------------------------------------------------------
extern "C" void kernel_launch(void* const* d_in, const int* in_sizes, int n_in,
                              void* d_out, int out_size, void* d_ws, size_t ws_size,
                              hipStream_t stream) {
  const float* pred = (const float*)d_in[0];   // [2,8,361,720]
  const float* targ = (const float*)d_in[1];   // [2,8,361,720]
  const float* wts  = (const float*)d_in[2];   // [8]
  const float* leg  = (const float*)d_in[3];   // [361,361,361]
  const float* wq   = (const float*)d_in[4];   // [361]
  float* out = (float*)d_out;

  float4* GG = (float4*)d_ws;                            // [360][361][16] float4
  float*  S  = (float*)(GG + (size_t)360 * NLAT * 16);   // [16][360][4]

  hipMemsetAsync(S, 0, (size_t)16 * 360 * 4 * sizeof(float), stream);

  dft_kernel<<<16 * 181, 192, 0, stream>>>(pred, targ, wq, GG);

  // 2208 = sum over 23 l-tiles of 8*(lt+1) m-blocks (2 m each)
  leg_kernel<<<2208, 128, 0, stream>>>(leg, GG, S);

  loss_kernel<<<1, 256, 0, stream>>>(S, wts, out);
}